// Round 8
// baseline (121.874 us; speedup 1.0000x reference)
//
#include <hip/hip_runtime.h>
#include <stdint.h>

#define NB 16
#define NN 25200
#define NCLS 80
#define NROW 85
#define KPRE 1000
#define MAXDET 300
#define CONF_T 0.25f
#define IOU_T 0.45f
#define GCAP 2048

typedef unsigned long long u64;
typedef unsigned int u32;
typedef unsigned short u16;
typedef unsigned char u8;

// Descending-order sortable key: higher score -> smaller key; ties by index.
__device__ __forceinline__ u32 desc_key(float s) {
  u32 u = __float_as_uint(s);
  u = (u & 0x80000000u) ? ~u : (u | 0x80000000u);
  return ~u;
}
__device__ __forceinline__ float inv_key(u32 k) {
  u32 u = ~k;
  u32 o = (u & 0x80000000u) ? (u & 0x7fffffffu) : ~u;
  return __uint_as_float(o);
}

// ---------------- Kernel 0: zero the global histograms ----------------
__global__ __launch_bounds__(1024) void k_zero(u32* __restrict__ gHist) {
  gHist[blockIdx.x * 1024 + threadIdx.x] = 0;
}

// ------- Kernel 1: decode (LDS-staged coalesced) + fused histogram -------
__global__ __launch_bounds__(256) void k_decode(
    const float* __restrict__ pred, float* __restrict__ scores,
    int* __restrict__ clsArr, float4* __restrict__ boxes,
    u32* __restrict__ gHist) {
  __shared__ __align__(16) float lds[4][1360];
  __shared__ u32 h[4096];
  const int tid = threadIdx.x;
  const int wid = tid >> 6, lane = tid & 63;
  const int q = lane & 3, rl = lane >> 2;
  const int img = blockIdx.y;
  const u32 INVB = desc_key(-1.0f) >> 20;
  for (int t = tid; t < 4096; t += 256) h[t] = 0;
  float* L = lds[wid];
  const float* base = pred + (size_t)img * NN * NROW;
  const int waveRow0 = blockIdx.x * 256 + wid * 64;
  const int IMGF = NN * NROW;
  __syncthreads();
  for (int c = 0; c < 4; ++c) {
    const int row0 = waveRow0 + c * 16;
    const int fbase = row0 * NROW;
#pragma unroll
    for (int k = 0; k < 5; ++k) {
      int off = k * 256 + lane * 4;
      int src = (fbase + off + 4 <= IMGF) ? (fbase + off) : 0;
      float4 v;
      __builtin_memcpy(&v, base + src, 16);
      *(float4*)(L + off) = v;
    }
    if (lane < 20) {
      int off = 1280 + lane * 4;
      int src = (fbase + off + 4 <= IMGF) ? (fbase + off) : 0;
      float4 v;
      __builtin_memcpy(&v, base + src, 16);
      *(float4*)(L + off) = v;
    }
    __syncthreads();
    const int row = row0 + rl;
    const bool rowOK = (row < NN);
    const float* R = L + rl * 85;
    float obj = R[4];
    float best = -1.0f;
    int bj = 0;
    const int j0 = q * 20;
#pragma unroll
    for (int jj = 0; jj < 20; ++jj) {
      float v = __fmul_rn(R[5 + j0 + jj], obj);
      if (v > best) { best = v; bj = j0 + jj; }
    }
#pragma unroll
    for (int d = 1; d < 4; d <<= 1) {
      float b2 = __shfl_xor(best, d, 64);
      int j2 = __shfl_xor(bj, d, 64);
      if (b2 > best || (b2 == best && j2 < bj)) { best = b2; bj = j2; }
    }
    bool valid = (best > CONF_T);
    u64 bb = __ballot(q == 0 && rowOK && !valid);
    if (lane == 0 && bb) atomicAdd(&h[INVB], (u32)__popcll(bb));
    if (q == 0 && rowOK) {
      if (valid) atomicAdd(&h[desc_key(best) >> 20], 1u);
      int gid = img * NN + row;
      float x = R[0], y = R[1], w = R[2], hgt = R[3];
      float hx = __fmul_rn(w, 0.5f), hy = __fmul_rn(hgt, 0.5f);
      float4 bx;
      bx.x = __fsub_rn(x, hx);
      bx.y = __fsub_rn(y, hy);
      bx.z = __fadd_rn(x, hx);
      bx.w = __fadd_rn(y, hy);
      scores[gid] = valid ? best : -1.0f;
      clsArr[gid] = bj;
      boxes[gid] = bx;
    }
    __syncthreads();
  }
  for (int t = tid; t < 4096; t += 256) {
    u32 v = h[t];
    if (v) atomicAdd(&gHist[img * 4096 + t], v);
  }
}

// ------- Kernel 2: gather top-1000 + class-group, write sorted SoA -------
__global__ __launch_bounds__(1024) void k_gather(
    const float* __restrict__ scores, const int* __restrict__ clsArr,
    const float4* __restrict__ boxes, const u32* __restrict__ gHist,
    u64* __restrict__ keyS, float* __restrict__ x1S, float* __restrict__ y1S,
    float* __restrict__ x2S, float* __restrict__ y2S, u32* __restrict__ clsS,
    u32* __restrict__ aliveS, u32* __restrict__ clsStartG) {
  const int img = blockIdx.x;
  const int tid = threadIdx.x;
  const int lane = tid & 63;
  const float* sc = scores + (size_t)img * NN;
  const size_t imgN = (size_t)img * NN;
  const int obase = img * 1024;

  __shared__ u64 gbuf[GCAP];      // 16 KB
  __shared__ u64 key64[1024];     // 8 KB
  __shared__ u64 tl[256];         // 2 KB
  __shared__ u8 dead[GCAP];       // 2 KB
  __shared__ u8 clsV[1024];
  __shared__ u16 clsList[1024];   // 2 KB
  __shared__ u32 clsCnt[NCLS];
  __shared__ u32 clsStart[NCLS + 1];
  __shared__ u32 subhist[256];
  __shared__ u32 wt[16], wt2[4];
  __shared__ u32 sB, sKr, sThr, sTake, sCnt, sTieCnt, sPcnt;

  if (tid == 0) { sCnt = 0; sTieCnt = 0; sPcnt = 0; }
  if (tid < NCLS) clsCnt[tid] = 0;
  dead[tid] = 0;
  dead[tid + 1024] = 0;

  // ---- P: prefetch keys ----
  u32 kk[25];
#pragma unroll
  for (int t = 0; t < 25; ++t) {
    int n = tid + t * 1024;
    kk[t] = (n < NN) ? desc_key(sc[n]) : 0xFFFFFFFFu;
  }

  // ---- A: 12-bit bucket of the 1000th key (shfl scan over 4096 buckets) ----
  uint4 hv = *(const uint4*)(gHist + (size_t)img * 4096 + tid * 4);
  u32 s4 = hv.x + hv.y + hv.z + hv.w;
  u32 incl = s4;
#pragma unroll
  for (int d = 1; d < 64; d <<= 1) {
    u32 o = __shfl_up(incl, (unsigned)d, 64);
    if (lane >= d) incl += o;
  }
  if (lane == 63) wt[tid >> 6] = incl;
  __syncthreads();
  {
    u32 woff = 0;
    int w = tid >> 6;
    for (int x = 0; x < w; ++x) woff += wt[x];
    u32 P = woff + incl - s4;
    if (P < KPRE && P + s4 >= KPRE) {
      u32 cacc = P, b = 3;
      if (cacc + hv.x >= KPRE) b = 0;
      else {
        cacc += hv.x;
        if (cacc + hv.y >= KPRE) b = 1;
        else {
          cacc += hv.y;
          if (cacc + hv.z >= KPRE) b = 2;
          else cacc += hv.z;
        }
      }
      sB = tid * 4 + b;
      sKr = KPRE - cacc;
    }
  }
  if (tid < 256) subhist[tid] = 0;
  __syncthreads();
  const u32 B = sB;
  const u32 Kr = sKr;

  // ---- A2: 8-bit refinement inside bucket B ----
#pragma unroll
  for (int t = 0; t < 25; ++t)
    if ((kk[t] >> 20) == B) atomicAdd(&subhist[(kk[t] >> 12) & 255], 1u);
  __syncthreads();
  {
    u32 myc = (tid < 256) ? subhist[tid] : 0;
    u32 inc2 = myc;
#pragma unroll
    for (int d = 1; d < 64; d <<= 1) {
      u32 o = __shfl_up(inc2, (unsigned)d, 64);
      if (lane >= d) inc2 += o;
    }
    if (tid < 256 && lane == 63) wt2[tid >> 6] = inc2;
    __syncthreads();
    if (tid < 256) {
      u32 off = 0;
      int w = tid >> 6;
      for (int x = 0; x < w; ++x) off += wt2[x];
      u32 inc = off + inc2, exc = inc - myc;
      if (exc < Kr && inc >= Kr) {
        sThr = (B << 8) | (u32)tid;
        sTake = Kr - exc;
      }
    }
  }
  __syncthreads();
  const u32 thr = sThr;
  const u32 take = sTake;

  // ---- C: gather all keys with 20-bit prefix <= thr ----
#pragma unroll
  for (int t = 0; t < 25; ++t) {
    bool g = (kk[t] >> 12) <= thr;
    u64 bb = __ballot(g);
    if (bb) {
      int ldr = __ffsll((long long)bb) - 1;
      u32 base = 0;
      if (lane == ldr) base = atomicAdd(&sCnt, (u32)__popcll(bb));
      base = __shfl(base, ldr, 64);
      if (g) {
        u32 pos = base + (u32)__popcll(bb & ((1ull << lane) - 1ull));
        if (pos < GCAP) gbuf[pos] = ((u64)kk[t] << 32) | (u32)(tid + t * 1024);
      }
    }
  }
  __syncthreads();
  const u32 cnt = sCnt < GCAP ? sCnt : GCAP;

  // ---- T: exact tie resolution at the threshold slot ----
  for (u32 t = tid; t < cnt; t += 1024) {
    if ((u32)(gbuf[t] >> 44) == thr) {
      u32 s = atomicAdd(&sTieCnt, 1u);
      if (s < 256) tl[s] = gbuf[t];
    }
  }
  __syncthreads();
  if (sTieCnt > take) {
    u32 tc = sTieCnt < 256 ? sTieCnt : 256;
    for (u32 t = tid; t < cnt; t += 1024) {
      if ((u32)(gbuf[t] >> 44) == thr) {
        u64 mine = gbuf[t];
        u32 r = 0;
        for (u32 o = 0; o < tc; ++o) r += (tl[o] < mine) ? 1u : 0u;
        if (r >= take) dead[t] = 1;
      }
    }
  }
  __syncthreads();

  // ---- E: compact participants (exactly KPRE) into key64/clsV ----
  for (u32 t = tid; t < cnt; t += 1024) {
    if (!dead[t]) {
      u32 p = atomicAdd(&sPcnt, 1u);
      if (p < 1024) {
        u64 e = gbuf[t];
        key64[p] = e;
        clsV[p] = (u8)clsArr[imgN + (u32)e];
      }
    }
  }
  __syncthreads();
  const int Pcnt = (int)(sPcnt < 1024 ? sPcnt : 1024);

  // ---- F: class counts + starts + in-class rank ----
  int myC = -1;
  u32 arb = 0;
  if (tid < Pcnt) {
    myC = (int)clsV[tid];
    arb = atomicAdd(&clsCnt[myC], 1u);
  }
  __syncthreads();
  if (tid < 128) {  // 2-wave scan over 80 class counts
    u32 v = (tid < NCLS) ? clsCnt[tid] : 0;
    u32 inc = v;
#pragma unroll
    for (int d = 1; d < 64; d <<= 1) {
      u32 o = __shfl_up(inc, (unsigned)d, 64);
      if (lane >= d) inc += o;
    }
    if (lane == 63) wt[tid >> 6] = inc;
  }
  __syncthreads();
  if (tid < 128) {
    u32 v = (tid < NCLS) ? clsCnt[tid] : 0;
    u32 inc = v;
#pragma unroll
    for (int d = 1; d < 64; d <<= 1) {
      u32 o = __shfl_up(inc, (unsigned)d, 64);
      if (lane >= d) inc += o;
    }
    u32 off = (tid >= 64) ? wt[0] : 0;
    if (tid <= NCLS) clsStart[tid] = off + inc - v;  // exclusive prefix
    if (tid == NCLS - 1) clsStart[NCLS] = off + inc;
  }
  __syncthreads();
  if (tid < Pcnt) clsList[clsStart[myC] + arb] = (u16)tid;
  __syncthreads();

  // ---- W: rank within class, write global SoA in class-sorted order ----
  if (tid < Pcnt) {
    u32 s = clsStart[myC], e2 = clsStart[myC + 1];
    u64 myk = key64[tid];
    u32 r = 0;
    for (u32 q = s; q < e2; ++q) r += (key64[clsList[q]] < myk) ? 1u : 0u;
    u32 p = s + r;
    u64 e = myk;
    u32 n = (u32)e;
    float4 bx = boxes[imgN + n];
    keyS[obase + p] = e;
    x1S[obase + p] = bx.x;
    y1S[obase + p] = bx.y;
    x2S[obase + p] = bx.z;
    y2S[obase + p] = bx.w;
    clsS[obase + p] = (u32)myC;
    aliveS[obase + p] = (inv_key((u32)(e >> 32)) > CONF_T) ? 1u : 0u;
  } else {
    keyS[obase + tid] = ~0ull;
    aliveS[obase + tid] = 0;
  }
  if (tid < NCLS + 1) clsStartG[img * 128 + tid] = clsStart[tid];
}

// ------- Kernel 3: per-(image,class) greedy NMS, register-resident -------
__global__ __launch_bounds__(64) void k_nmscls(
    const u64* __restrict__ keyS, const float* __restrict__ x1S,
    const float* __restrict__ y1S, const float* __restrict__ x2S,
    const float* __restrict__ y2S, u32* __restrict__ aliveS,
    const u32* __restrict__ clsStartG) {
  const int c = blockIdx.x;
  const int img = blockIdx.y;
  const int lane = threadIdx.x;
  const u32 s = clsStartG[img * 128 + c];
  const u32 e = clsStartG[img * 128 + c + 1];
  const int cnt = (int)(e - s);
  if (cnt <= 1) return;
  const int base = img * 1024 + (int)s;
  const float offc = __fmul_rn((float)c, 4096.0f);

  if (cnt <= 64) {
    bool has = lane < cnt;
    float x1 = 0.f, y1 = 0.f, x2 = 0.f, y2 = 0.f, ar = 0.f;
    u32 av = 0;
    if (has) {
      x1 = __fadd_rn(x1S[base + lane], offc);
      y1 = __fadd_rn(y1S[base + lane], offc);
      x2 = __fadd_rn(x2S[base + lane], offc);
      y2 = __fadd_rn(y2S[base + lane], offc);
      ar = __fmul_rn(__fsub_rn(x2, x1), __fsub_rn(y2, y1));
      av = aliveS[base + lane];
    }
    for (int i = 0; i < cnt - 1; ++i) {
      u32 ai = (u32)__shfl((int)av, i, 64);
      if (!ai) continue;  // wave-uniform
      float ix1 = __shfl(x1, i, 64), iy1 = __shfl(y1, i, 64);
      float ix2 = __shfl(x2, i, 64), iy2 = __shfl(y2, i, 64);
      float ia = __shfl(ar, i, 64);
      if (lane > i && av) {
        float xx1 = fmaxf(ix1, x1), yy1 = fmaxf(iy1, y1);
        float xx2 = fminf(ix2, x2), yy2 = fminf(iy2, y2);
        float ww = fmaxf(__fsub_rn(xx2, xx1), 0.0f);
        float hh = fmaxf(__fsub_rn(yy2, yy1), 0.0f);
        float inter = __fmul_rn(ww, hh);
        float den = __fadd_rn(__fsub_rn(__fadd_rn(ia, ar), inter), 1e-9f);
        if (inter > __fmul_rn(IOU_T, den)) av = 0;
      }
    }
    if (has) aliveS[base + lane] = av;
  } else {
    __shared__ float lx1[1024], ly1[1024], lx2[1024], ly2[1024], la[1024];
    __shared__ u8 lal[1024];
    for (int t = lane; t < cnt; t += 64) {
      float a1 = __fadd_rn(x1S[base + t], offc);
      float b1 = __fadd_rn(y1S[base + t], offc);
      float a2 = __fadd_rn(x2S[base + t], offc);
      float b2 = __fadd_rn(y2S[base + t], offc);
      lx1[t] = a1; ly1[t] = b1; lx2[t] = a2; ly2[t] = b2;
      la[t] = __fmul_rn(__fsub_rn(a2, a1), __fsub_rn(b2, b1));
      lal[t] = (u8)aliveS[base + t];
    }
    __syncthreads();
    for (int i = 0; i < cnt - 1; ++i) {
      if (!lal[i]) continue;
      float ix1 = lx1[i], iy1 = ly1[i], ix2 = lx2[i], iy2 = ly2[i], ia = la[i];
      for (int j = i + 1 + lane; j < cnt; j += 64) {
        if (lal[j]) {
          float xx1 = fmaxf(ix1, lx1[j]), yy1 = fmaxf(iy1, ly1[j]);
          float xx2 = fminf(ix2, lx2[j]), yy2 = fminf(iy2, ly2[j]);
          float ww = fmaxf(__fsub_rn(xx2, xx1), 0.0f);
          float hh = fmaxf(__fsub_rn(yy2, yy1), 0.0f);
          float inter = __fmul_rn(ww, hh);
          float den = __fadd_rn(__fsub_rn(__fadd_rn(ia, la[j]), inter), 1e-9f);
          if (inter > __fmul_rn(IOU_T, den)) lal[j] = 0;
        }
      }
    }
    __syncthreads();
    for (int t = lane; t < cnt; t += 64) aliveS[base + t] = lal[t];
  }
}

// ------- Kernel 4: survivor rank-by-count + output write -------
__global__ __launch_bounds__(256) void k_out(
    const u64* __restrict__ keyS, const float* __restrict__ x1S,
    const float* __restrict__ y1S, const float* __restrict__ x2S,
    const float* __restrict__ y2S, const u32* __restrict__ clsS,
    const u32* __restrict__ aliveS, float* __restrict__ out) {
  const int img = blockIdx.x;
  const int tid = threadIdx.x;
  const int obase = img * 1024;
  __shared__ u64 svKey[1024];
  __shared__ u16 svP[1024];
  __shared__ u32 sCnt;
  if (tid == 0) sCnt = 0;
  float* outImg = out + (size_t)img * MAXDET * 6;
  for (int t = tid; t < MAXDET * 6; t += 256) outImg[t] = 0.0f;
  __syncthreads();
  for (int p = tid; p < 1024; p += 256) {
    if (aliveS[obase + p]) {
      u32 s = atomicAdd(&sCnt, 1u);
      svKey[s] = keyS[obase + p];
      svP[s] = (u16)p;
    }
  }
  __syncthreads();
  const u32 S = sCnt;
  for (u32 s = tid; s < S; s += 256) {
    u64 myk = svKey[s];
    u32 r = 0;
    for (u32 o = 0; o < S; ++o) r += (svKey[o] < myk) ? 1u : 0u;
    if (r < MAXDET) {
      int p = (int)svP[s];
      float* o6 = outImg + (size_t)r * 6;
      o6[0] = x1S[obase + p];
      o6[1] = y1S[obase + p];
      o6[2] = x2S[obase + p];
      o6[3] = y2S[obase + p];
      o6[4] = inv_key((u32)(svKey[s] >> 32));
      o6[5] = (float)clsS[obase + p];
    }
  }
}

extern "C" void kernel_launch(void* const* d_in, const int* in_sizes, int n_in,
                              void* d_out, int out_size, void* d_ws, size_t ws_size,
                              hipStream_t stream) {
  const float* pred = (const float*)d_in[0];
  char* ws = (char*)d_ws;
  size_t off = 0;
  float* scores = (float*)(ws + off); off += (size_t)NB * NN * 4;
  int* clsArr = (int*)(ws + off); off += (size_t)NB * NN * 4;
  float4* boxes = (float4*)(ws + off); off += (size_t)NB * NN * 16;
  u32* gHist = (u32*)(ws + off); off += (size_t)NB * 4096 * 4;
  u64* keyS = (u64*)(ws + off); off += (size_t)NB * 1024 * 8;
  float* x1S = (float*)(ws + off); off += (size_t)NB * 1024 * 4;
  float* y1S = (float*)(ws + off); off += (size_t)NB * 1024 * 4;
  float* x2S = (float*)(ws + off); off += (size_t)NB * 1024 * 4;
  float* y2S = (float*)(ws + off); off += (size_t)NB * 1024 * 4;
  u32* clsS = (u32*)(ws + off); off += (size_t)NB * 1024 * 4;
  u32* aliveS = (u32*)(ws + off); off += (size_t)NB * 1024 * 4;
  u32* clsStartG = (u32*)(ws + off); off += (size_t)NB * 128 * 4;
  if (off > ws_size) return;

  float* outp = (float*)d_out;
  k_zero<<<NB * 4096 / 1024, 1024, 0, stream>>>(gHist);
  dim3 gridD((NN + 255) / 256, NB);
  k_decode<<<gridD, 256, 0, stream>>>(pred, scores, clsArr, boxes, gHist);
  k_gather<<<NB, 1024, 0, stream>>>(scores, clsArr, boxes, gHist, keyS, x1S,
                                    y1S, x2S, y2S, clsS, aliveS, clsStartG);
  dim3 gridN(NCLS, NB);
  k_nmscls<<<gridN, 64, 0, stream>>>(keyS, x1S, y1S, x2S, y2S, aliveS,
                                     clsStartG);
  k_out<<<NB, 256, 0, stream>>>(keyS, x1S, y1S, x2S, y2S, clsS, aliveS, outp);
}